// Round 3
// baseline (46.825 us; speedup 1.0000x reference)
//
#include <hip/hip_runtime.h>
#include <hip/hip_bf16.h>

// ---- problem constants ----
#define BATCH  65536
#define KREAL  784          // 28*28 = GEMM-K (conv folded into Weff)
#define BK     64
#define NCHUNK 13
#define KPAD   (NCHUNK*BK)  // 832
#define HID    128
#define NOUT   10
#define BM     128          // rows per block
#define NTHR   512          // 8 waves

using f32x4  = __attribute__((ext_vector_type(4))) float;
using short8 = __attribute__((ext_vector_type(8))) short;   // 8 bf16
using f4     = __attribute__((ext_vector_type(4))) float;

__device__ inline short f2b(float f) {
    union { __hip_bfloat16 h; short s; } u;
    u.h = __float2bfloat16(f);               // hardware RNE cvt
    return u.s;
}

// global -> LDS direct copy, 16 B per lane. gp: per-lane global addr,
// lp: wave-uniform LDS base (HW writes base + lane*16).
#define GLDS16(gp, lp) \
    __builtin_amdgcn_global_load_lds((const __attribute__((address_space(1))) void*)(gp), \
                                     (__attribute__((address_space(3))) void*)(lp), 16, 0, 0)

// ---------------------------------------------------------------------------
// Prep: weff_sw = conv folded into w1, bf16, CHUNK-MAJOR and PRE-SWIZZLED:
//   weff_sw[ic][r][gsw][e] holds logical Weff[r][ic*64 + ((gsw^(r&7))*8 + e)]
// so a linear 16 KB copy of chunk ic yields the swizzled LDS B-tile.
// w2p[16][128] = w2 zero-padded (bf16).
// ---------------------------------------------------------------------------
__global__ void prep_kernel(const float* __restrict__ conv_w,
                            const float* __restrict__ w1,
                            const float* __restrict__ w2,
                            unsigned short* __restrict__ weff_sw,
                            unsigned short* __restrict__ w2p)
{
    const int NW = NCHUNK * HID * BK;        // 106496
    int idx = blockIdx.x * 256 + threadIdx.x;
    if (idx < NW) {
        int ic  = idx >> 13;                 // /(128*64)
        int rem = idx & 8191;
        int r   = rem >> 6;
        int cc  = rem & 63;
        int g   = (cc >> 3) ^ (r & 7);       // logical 8-elem group
        int k   = ic * BK + g * 8 + (cc & 7);
        float acc = 0.f;
        if (k < KREAL) {
            int rr = k / 28, c = k - rr * 28;
            #pragma unroll
            for (int di = 0; di < 3; ++di) {
                int i = rr - di;
                if (i >= 0 && i < 26) {
                    #pragma unroll
                    for (int dj = 0; dj < 3; ++dj) {
                        int j = c - dj;
                        if (j >= 0 && j < 26)
                            acc = fmaf(w1[r * 676 + i * 26 + j], conv_w[di * 3 + dj], acc);
                    }
                }
            }
        }
        weff_sw[idx] = (unsigned short)f2b(acc);
    } else {
        int k = idx - NW;
        if (k < 16 * HID) {
            int o = k >> 7, c = k & 127;
            w2p[k] = (unsigned short)f2b((o < NOUT) ? w2[o * HID + c] : 0.f);
        }
    }
}

// ---------------------------------------------------------------------------
// Fused: relu(x @ Weff^T + b1) @ w2p^T + b2
// 512 thr (8 waves), BM=128. A: direct global->reg (no LDS, no reuse to
// exploit). B: LDS double-buffered via global_load_lds of pre-swizzled weff.
// One barrier per chunk; prefetched loads get a full chunk to land before
// the vmcnt(0) drain at the next barrier.
// ---------------------------------------------------------------------------
__global__ __launch_bounds__(NTHR, 4)
void fused_mlp_kernel(const float* __restrict__ x,
                      const float* __restrict__ b1,
                      const float* __restrict__ b2,
                      const unsigned short* __restrict__ weff_sw,
                      const unsigned short* __restrict__ w2p,
                      float* __restrict__ out)
{
    __shared__ __align__(16) unsigned short smem[16384];   // 32 KB
    unsigned short* bufB0 = smem;            // [128][64] swizzled, chunk even
    unsigned short* bufB1 = smem + 8192;     // chunk odd
    unsigned short* ldsH  = smem;            // [128][128] swizzled, aliased after loop

    const int tid  = threadIdx.x;
    const int wv   = tid >> 6;
    const int lane = tid & 63;
    const int lo   = lane & 15;
    const int hi   = lane >> 4;
    const int row0 = blockIdx.x * BM;
    const int wr0  = wv * 16;

    f32x4 acc[8];
    #pragma unroll
    for (int t = 0; t < 8; ++t) acc[t] = (f32x4){0.f, 0.f, 0.f, 0.f};

    const f4 fz = {0.f, 0.f, 0.f, 0.f};
    const float* arow = x + (long)(row0 + wr0 + lo) * KREAL;   // this lane's A row

    // load the 4 x f4 (16 floats) of A this lane needs for one chunk
    auto loadA = [&](int kbase, f4* v) {
        #pragma unroll
        for (int m = 0; m < 4; ++m) {
            int col = kbase + (m >> 1) * 32 + hi * 8 + (m & 1) * 4;
            v[m] = (col < KREAL) ? *(const f4*)(arow + col) : fz;
        }
    };
    auto stageB = [&](int ic, unsigned short* dst) {
        const char* src = (const char*)(weff_sw + ic * (HID * BK));
        int o0 = wv * 1024 + lane * 16;
        GLDS16(src + o0,        (char*)dst + wv * 1024);
        GLDS16(src + o0 + 8192, (char*)dst + wv * 1024 + 8192);
    };

    // ---- prologue: chunk 0 in flight ----
    f4 av[2][4];
    loadA(0, av[0]);
    stageB(0, bufB0);

    #pragma unroll
    for (int ic = 0; ic < NCHUNK; ++ic) {
        __syncthreads();   // drains own vmcnt -> B[ic]+A[ic] arrived; all waves done with buf^1
        const unsigned short* Bc = (ic & 1) ? bufB1 : bufB0;
        unsigned short*       Bn = (ic & 1) ? bufB0 : bufB1;
        if (ic + 1 < NCHUNK) {
            stageB(ic + 1, Bn);
            loadA((ic + 1) * BK, av[(ic + 1) & 1]);
        }
        // cvt this chunk's A to bf16 fragments
        short8 af[2];
        #pragma unroll
        for (int kk = 0; kk < 2; ++kk)
            #pragma unroll
            for (int e = 0; e < 4; ++e) {
                af[kk][e]     = f2b(av[ic & 1][kk * 2][e]);
                af[kk][4 + e] = f2b(av[ic & 1][kk * 2 + 1][e]);
            }
        // 2 k-substeps x 8 n-tiles
        #pragma unroll
        for (int kk = 0; kk < 2; ++kk) {
            const int gA = kk * 4 + hi;
            #pragma unroll
            for (int t = 0; t < 8; ++t) {
                const int ob = t * 16 + lo;
                short8 bfrag = *(const short8*)&Bc[ob * BK + ((gA ^ (ob & 7)) << 3)];
                acc[t] = __builtin_amdgcn_mfma_f32_16x16x32_bf16(af[kk], bfrag, acc[t], 0, 0, 0);
            }
        }
    }

    __syncthreads();       // all waves done reading bufB before ldsH alias write

    // ---- FC1 epilogue: +b1, ReLU, h -> swizzled ldsH (own-wave rows only) ----
    // C/D layout: col = lane&15, row = (lane>>4)*4 + reg
    #pragma unroll
    for (int t = 0; t < 8; ++t) {
        float bias = b1[t * 16 + lo];
        #pragma unroll
        for (int j = 0; j < 4; ++j) {
            float hv = acc[t][j] + bias;
            hv = hv > 0.f ? hv : 0.f;
            int rloc = wr0 + hi * 4 + j;
            int col  = t * 16 + lo;
            int g    = col >> 3, e = col & 7;
            ldsH[rloc * HID + ((g ^ (rloc & 7)) << 3) + e] = (unsigned short)f2b(hv);
        }
    }
    // wave reads only its own writes -> compiler lgkmcnt suffices, no barrier

    // ---- FC2: h[16x128] @ w2p^T[128x16] per wave, 4 MFMAs ----
    f32x4 acc2 = (f32x4){0.f, 0.f, 0.f, 0.f};
    #pragma unroll
    for (int kk = 0; kk < 4; ++kk) {
        int r = wr0 + lo;
        int g = kk * 4 + hi;
        short8 ha = *(const short8*)&ldsH[r * HID + ((g ^ (r & 7)) << 3)];
        short8 wb = *(const short8*)(w2p + lo * HID + kk * 32 + hi * 8);
        acc2 = __builtin_amdgcn_mfma_f32_16x16x32_bf16(ha, wb, acc2, 0, 0, 0);
    }
    if (lo < NOUT) {
        float bb = b2[lo];
        #pragma unroll
        for (int j = 0; j < 4; ++j) {
            int grow = row0 + wr0 + hi * 4 + j;
            out[grow * NOUT + lo] = acc2[j] + bb;
        }
    }
}

// ---------------------------------------------------------------------------
extern "C" void kernel_launch(void* const* d_in, const int* in_sizes, int n_in,
                              void* d_out, int out_size, void* d_ws, size_t ws_size,
                              hipStream_t stream)
{
    const float* x      = (const float*)d_in[0];
    const float* conv_w = (const float*)d_in[1];
    const float* w1     = (const float*)d_in[2];
    const float* b1     = (const float*)d_in[3];
    const float* w2     = (const float*)d_in[4];
    const float* b2     = (const float*)d_in[5];
    float* out = (float*)d_out;

    unsigned short* weff_sw = (unsigned short*)d_ws;         // 13*128*64 bf16
    unsigned short* w2p     = weff_sw + NCHUNK * HID * BK;   // 16*128 bf16

    const int prep_total = NCHUNK * HID * BK + 16 * HID;     // 108544
    prep_kernel<<<(prep_total + 255) / 256, 256, 0, stream>>>(conv_w, w1, w2, weff_sw, w2p);
    fused_mlp_kernel<<<BATCH / BM, NTHR, 0, stream>>>(x, b1, b2, weff_sw, w2p, out);
}